// Round 7
// baseline (20901.208 us; speedup 1.0000x reference)
//
#include <hip/hip_runtime.h>

// ---------------- problem constants ----------------
#define B_ 8
#define S_ 128
#define H_ 512
#define G_ 2048   // 4H
#define MEL_ 80

// ---------------- ws layout (32-bit word offsets) ----------------
#define FLG_DEC    0        // decoder flags idx 0..39 (words 0..639)
#define DONE_DEC   640      // done flags (each own line)
#define DONE_L0    656
#define DONE_L1    672
#define FLG_L0     2048     // lstm0: dir0 @ +0, dir1 @ +1024
#define FLG_L1     4096     // lstm1
#define OFF_H0S    8192                 // lstm0 h [dir][pingpong][b][512] = 16384
#define OFF_H1S    (OFF_H0S + 16384)    // 16384
#define OFF_DH     (OFF_H1S + 16384)    // dec h [b][512] = 4096
#define OFF_DIN    (OFF_DH + 4096)      // din [b][128] = 1024 (80 used/row)
#define OFF_HW     (OFF_DIN + 1024)     // (unused) 4096
#define OFF_CTX    (OFF_HW + 4096)      // [b][1024] = 8192
#define ZERO_WORDS (OFF_CTX + 8192)     // = 58368 = 228*256
#define OFF_X0     58368                        // [bs][512]   524288
#define OFF_GX0F   (OFF_X0 + 524288)            // [bs][2048] 2097152
#define OFF_GX0B   (OFF_GX0F + 2097152)
#define OFF_H0     (OFF_GX0B + 2097152)         // [bs][1024] 1048576
#define OFF_GX1F   (OFF_H0 + 1048576)
#define OFF_GX1B   (OFF_GX1F + 2097152)
#define OFF_ENC    (OFF_GX1B + 2097152)         // [bs][1024] 1048576
#define OFF_ENCP   (OFF_ENC + 1048576)          // [bs][512]   524288

// ---------------- helpers ----------------
__device__ __forceinline__ float sigm_f(float x) {
    x = fminf(fmaxf(x, -30.f), 30.f);
    return 1.f / (1.f + __expf(-x));
}
__device__ __forceinline__ float tanh_f(float x) {
    x = fminf(fmaxf(x, -15.f), 15.f);
    float e = __expf(2.f * x);
    return (e - 1.f) / (e + 1.f);
}

__device__ __forceinline__ void agw_u(unsigned* p, unsigned v) {
    __hip_atomic_store(p, v, __ATOMIC_RELAXED, __HIP_MEMORY_SCOPE_AGENT);
}
__device__ __forceinline__ unsigned agr_u(const unsigned* p) {
    return __hip_atomic_load(p, __ATOMIC_RELAXED, __HIP_MEMORY_SCOPE_AGENT);
}
__device__ __forceinline__ void agw_f(float* p, float v) {
    agw_u((unsigned*)p, __float_as_uint(v));
}
__device__ __forceinline__ float agr_f(const float* p) {
    return __uint_as_float(agr_u((const unsigned*)p));
}

// acquire fence: one wave issues an ACQUIRE atomic load -> cache invalidate
// once; subsequent NORMAL loads fetch fresh data with full-line bandwidth.
__device__ __forceinline__ void acq_fence(const unsigned* anyflag) {
    __syncthreads();
    if (threadIdx.x < 64)
        (void)__hip_atomic_load(anyflag, __ATOMIC_ACQUIRE, __HIP_MEMORY_SCOPE_AGENT);
    __syncthreads();
}

// full flag barrier (LSTM): arrive own line, poll peers, acquire.
__device__ __forceinline__ void flag_barrier(unsigned* flags, int wg, unsigned phase, int nwg) {
    asm volatile("s_waitcnt vmcnt(0) lgkmcnt(0)" ::: "memory");
    __syncthreads();
    if (threadIdx.x == 0)
        agw_u(flags + wg * 16, phase);
    if ((int)threadIdx.x < nwg) {
        while (agr_u(flags + threadIdx.x * 16) < phase)
            __builtin_amdgcn_s_sleep(4);
    }
    __syncthreads();
    if (threadIdx.x < 64)
        (void)__hip_atomic_load(flags + wg * 16, __ATOMIC_ACQUIRE, __HIP_MEMORY_SCOPE_AGENT);
    __syncthreads();
}

// arrival only
__device__ __forceinline__ void arrive(unsigned* flags, int wg, unsigned phase) {
    asm volatile("s_waitcnt vmcnt(0) lgkmcnt(0)" ::: "memory");
    __syncthreads();
    if (threadIdx.x == 0)
        agw_u(flags + wg * 16, phase);
}

// heater: register-only FMA spin until *done != 0. Keeps the clock governor
// at high frequency while the real WGs run the latency-bound recurrence.
// Iteration count is timing-dependent but writes nothing -> output unchanged.
__device__ __forceinline__ void heater_spin(const unsigned* done) {
    float x = (float)(threadIdx.x & 63) * 1.0000001f + 1.0f;
    const float y = 1.0000001f, z = 0.9999999f;
    while (agr_u(done) == 0) {
#pragma unroll 64
        for (int i = 0; i < 4096; ++i)
            x = fmaf(x, y, z);
    }
    asm volatile("" :: "v"(x));   // keep x live
}

// ---------------- zero init ----------------
__global__ __launch_bounds__(256) void zero_kernel(float* p) {
    p[blockIdx.x * 256 + threadIdx.x] = 0.f;
}

// ---------------- embedding ----------------
__global__ __launch_bounds__(256) void embed_kernel(const int* __restrict__ text,
                                                    const float* __restrict__ emb,
                                                    float* __restrict__ X) {
    int i = blockIdx.x * 256 + threadIdx.x;   // float4 id, 131072 total
    int bs = i >> 7;
    int h4 = i & 127;
    int ch = text[bs];
    ((float4*)X)[i] = ((const float4*)emb)[ch * 128 + h4];
}

// ---------------- f32 GEMM: C[M,N] = A[M,K] * W[N,K]^T + b1 (+ b2) ----------------
__global__ __launch_bounds__(256) void gemm_f32(const float* __restrict__ A, int lda,
                                                const float* __restrict__ W, int ldw,
                                                const float* __restrict__ b1,
                                                const float* __restrict__ b2,
                                                float* __restrict__ C, int ldc, int K) {
    __shared__ float As[32][68];
    __shared__ float Ws[32][68];
    int tid = threadIdx.x;
    int tx = tid & 15, ty = tid >> 4;
    int n0 = blockIdx.x * 64, m0 = blockIdx.y * 64;
    float acc[4][4] = {};
    int r  = tid >> 3;
    int c4 = (tid & 7) * 4;
    for (int k0 = 0; k0 < K; k0 += 32) {
        float4 a0 = *(const float4*)&A[(m0 + r) * lda + k0 + c4];
        float4 a1 = *(const float4*)&A[(m0 + r + 32) * lda + k0 + c4];
        float4 w0 = *(const float4*)&W[(n0 + r) * ldw + k0 + c4];
        float4 w1 = *(const float4*)&W[(n0 + r + 32) * ldw + k0 + c4];
        As[c4 + 0][r] = a0.x; As[c4 + 1][r] = a0.y; As[c4 + 2][r] = a0.z; As[c4 + 3][r] = a0.w;
        As[c4 + 0][r + 32] = a1.x; As[c4 + 1][r + 32] = a1.y; As[c4 + 2][r + 32] = a1.z; As[c4 + 3][r + 32] = a1.w;
        Ws[c4 + 0][r] = w0.x; Ws[c4 + 1][r] = w0.y; Ws[c4 + 2][r] = w0.z; Ws[c4 + 3][r] = w0.w;
        Ws[c4 + 0][r + 32] = w1.x; Ws[c4 + 1][r + 32] = w1.y; Ws[c4 + 2][r + 32] = w1.z; Ws[c4 + 3][r + 32] = w1.w;
        __syncthreads();
#pragma unroll 8
        for (int kk = 0; kk < 32; ++kk) {
            float4 av = *(const float4*)&As[kk][ty * 4];
            float4 wv = *(const float4*)&Ws[kk][tx * 4];
            acc[0][0] = fmaf(av.x, wv.x, acc[0][0]); acc[0][1] = fmaf(av.x, wv.y, acc[0][1]);
            acc[0][2] = fmaf(av.x, wv.z, acc[0][2]); acc[0][3] = fmaf(av.x, wv.w, acc[0][3]);
            acc[1][0] = fmaf(av.y, wv.x, acc[1][0]); acc[1][1] = fmaf(av.y, wv.y, acc[1][1]);
            acc[1][2] = fmaf(av.y, wv.z, acc[1][2]); acc[1][3] = fmaf(av.y, wv.w, acc[1][3]);
            acc[2][0] = fmaf(av.z, wv.x, acc[2][0]); acc[2][1] = fmaf(av.z, wv.y, acc[2][1]);
            acc[2][2] = fmaf(av.z, wv.z, acc[2][2]); acc[2][3] = fmaf(av.z, wv.w, acc[2][3]);
            acc[3][0] = fmaf(av.w, wv.x, acc[3][0]); acc[3][1] = fmaf(av.w, wv.y, acc[3][1]);
            acc[3][2] = fmaf(av.w, wv.z, acc[3][2]); acc[3][3] = fmaf(av.w, wv.w, acc[3][3]);
        }
        __syncthreads();
    }
#pragma unroll
    for (int i = 0; i < 4; ++i)
#pragma unroll
        for (int j = 0; j < 4; ++j) {
            int n = n0 + tx * 4 + j;
            int m = m0 + ty * 4 + i;
            float bias = b1[n] + (b2 ? b2[n] : 0.f);
            C[m * ldc + n] = acc[i][j] + bias;
        }
}

// ---------------- persistent bidirectional LSTM layer ----------------
// grid 256 WGs: 0..127 real (dir = wg>>6, slot = wg&63), 128..255 heaters.
__global__ __launch_bounds__(256) void lstm_kernel(const float* __restrict__ GXf,
                                                   const float* __restrict__ GXb,
                                                   const float* __restrict__ Whh_f,
                                                   const float* __restrict__ Whh_b,
                                                   float* __restrict__ Hout,
                                                   float* __restrict__ hstate,
                                                   unsigned* __restrict__ flagsL,
                                                   unsigned* __restrict__ done) {
    int wg = blockIdx.x;
    if (wg >= 128) { heater_spin(done); return; }

    int dir = wg >> 6;
    int slot = wg & 63;
    const float* GX  = dir ? GXb : GXf;
    const float* Whh = dir ? Whh_b : Whh_f;
    float* hs0 = hstate + dir * 8192;   // [pingpong][b][512]
    unsigned* flags = flagsL + dir * 1024;

    int tid = threadIdx.x;
    int q  = tid >> 6;
    int jj = (tid >> 3) & 7;
    int bb = tid & 7;
    int j   = slot * 8 + jj;
    int row = q * 512 + j;
    const float* wr = Whh + row * 512;

    __shared__ float hsh[8][516];
    __shared__ float gsh[4][8][8];

    float c_reg = 0.f;

    for (int t = 0; t < 128; ++t) {
        int st = dir ? (127 - t) : t;
        const float* hsr = hs0 + (t & 1) * 4096;
        float* hsw = hs0 + ((t & 1) ^ 1) * 4096;
        // stage h into LDS: NORMAL float4 loads (fresh after barrier's acquire)
#pragma unroll
        for (int u = 0; u < 4; ++u) {
            int n = tid + u * 256;           // 0..1023 float4s
            int b2 = n >> 7, k4 = n & 127;
            *(float4*)&hsh[b2][k4 * 4] = *(const float4*)(hsr + b2 * 512 + k4 * 4);
        }
        __syncthreads();

        float acc = GX[(bb * S_ + st) * G_ + row];
        float a0 = 0.f, a1 = 0.f, a2 = 0.f, a3 = 0.f;
#pragma unroll 8
        for (int k = 0; k < 512; k += 4) {
            float4 wv = *(const float4*)(wr + k);
            float4 hv = *(const float4*)&hsh[bb][k];
            a0 = fmaf(wv.x, hv.x, a0);
            a1 = fmaf(wv.y, hv.y, a1);
            a2 = fmaf(wv.z, hv.z, a2);
            a3 = fmaf(wv.w, hv.w, a3);
        }
        acc += (a0 + a1) + (a2 + a3);
        gsh[q][jj][bb] = acc;
        __syncthreads();

        if (q == 0) {
            float gi = gsh[0][jj][bb], gf = gsh[1][jj][bb];
            float gg = gsh[2][jj][bb], go = gsh[3][jj][bb];
            float c2 = sigm_f(gf) * c_reg + sigm_f(gi) * tanh_f(gg);
            float h2 = sigm_f(go) * tanh_f(c2);
            c_reg = c2;
            agw_f(hsw + bb * 512 + j, h2);
            Hout[(bb * S_ + st) * 1024 + dir * 512 + j] = h2;
        }
        flag_barrier(flags, slot, (unsigned)(t + 1), 64);
    }

    if (dir == 0 && slot == 0 && tid == 0)
        agw_u(done, 1u);
}

// ---------------- persistent attention decoder ----------------
// grid 256 WGs x 512 thr: 0..31 gate WGs, 32..39 attention WGs, 40..255 heaters.
// alpha (ph 2t+1): producers {gate 0..4 (mel/DIN), attn 32..39 (CTX)}.
// beta  (ph 2t+2): producers {gate 0..31 (DH)}; all real WGs wait.
union DecSMem {
    struct { float dh[8][516]; float gA[8][2][8][8]; float gM[4][2][8][8]; } a;
    struct { float dh2[512]; float hw[512]; float tmp[4][128]; float att[128]; float red[128]; } at;
    struct { float ctx[8][1028]; float din[8][132]; float gB[8][2][8][8]; } b;
};

__global__ __launch_bounds__(512) void decoder_kernel(float* __restrict__ ws,
                                                      const float* __restrict__ attn_W,
                                                      const float* __restrict__ attn_v,
                                                      const float* __restrict__ dec_Wih,
                                                      const float* __restrict__ dec_Whh,
                                                      const float* __restrict__ dec_bih,
                                                      const float* __restrict__ dec_bhh,
                                                      const float* __restrict__ mel_W,
                                                      const float* __restrict__ mel_b,
                                                      float* __restrict__ out, int T,
                                                      unsigned* __restrict__ flags,
                                                      unsigned* __restrict__ done) {
    int wg = blockIdx.x;     // 0..255
    if (wg >= 40) { heater_spin(done); return; }

    float* ENC  = ws + OFF_ENC;
    float* ENCP = ws + OFF_ENCP;
    float* DH   = ws + OFF_DH;
    float* DIN  = ws + OFF_DIN;
    float* CTX  = ws + OFF_CTX;

    int tid = threadIdx.x;   // 0..511

    __shared__ DecSMem sm;

    int q   = tid >> 6;
    int g   = q & 3;
    int kh2 = q >> 2;
    int jj  = (tid >> 3) & 7;
    int bb  = tid & 7;

    float bias0 = 0.f, bias1 = 0.f;
    if (wg < 32) {
        int r0 = g * 512 + wg * 16 + jj;
        bias0 = dec_bih[r0] + dec_bhh[r0];
        bias1 = dec_bih[r0 + 8] + dec_bhh[r0 + 8];
    }

    int ab = wg - 32;        // attention batch (wg>=32)

    float c_reg0 = 0.f, c_reg1 = 0.f;   // cell state (gate WGs, q==0)
    float hd0 = 0.f, hd1 = 0.f;         // Whh@h + bias (q<4)

    for (int t = 0; t < T; ++t) {
        unsigned ph1 = (unsigned)(2 * t + 1);
        unsigned ph2 = (unsigned)(2 * t + 2);

        // ================= phase A =================
        if (wg < 32) {
            acq_fence(flags + wg * 16);          // make prev-step DH visible
#pragma unroll
            for (int u = 0; u < 2; ++u) {
                int n = tid + u * 512;           // 0..1023 float4s
                int b2 = n >> 7, k4 = n & 127;
                *(float4*)&sm.a.dh[b2][k4 * 4] = *(const float4*)(DH + b2 * 512 + k4 * 4);
            }
            __syncthreads();

            // hdec partials: 2 j-columns per thread, k-half kh2
#pragma unroll
            for (int jc = 0; jc < 2; ++jc) {
                int row = g * 512 + wg * 16 + jc * 8 + jj;
                const float* wp = dec_Whh + (size_t)row * 512 + kh2 * 256;
                const float* hp = &sm.a.dh[bb][kh2 * 256];
                float a0 = 0.f, a1 = 0.f, a2 = 0.f, a3 = 0.f;
#pragma unroll 8
                for (int k = 0; k < 256; k += 4) {
                    float4 wv = *(const float4*)(wp + k);
                    float4 hv = *(const float4*)(hp + k);
                    a0 = fmaf(wv.x, hv.x, a0); a1 = fmaf(wv.y, hv.y, a1);
                    a2 = fmaf(wv.z, hv.z, a2); a3 = fmaf(wv.w, hv.w, a3);
                }
                sm.a.gA[q][jc][jj][bb] = (a0 + a1) + (a2 + a3);
            }
            // mel partials: WGs 0..4 cover 80 rows; q<4 = k-quarter
            if (wg < 5 && q < 4) {
#pragma unroll
                for (int jc = 0; jc < 2; ++jc) {
                    int mr = wg * 16 + jc * 8 + jj;
                    const float* wp = mel_W + (size_t)mr * 512 + q * 128;
                    const float* hp = &sm.a.dh[bb][q * 128];
                    float a0 = 0.f, a1 = 0.f, a2 = 0.f, a3 = 0.f;
#pragma unroll 8
                    for (int k = 0; k < 128; k += 4) {
                        float4 wv = *(const float4*)(wp + k);
                        float4 hv = *(const float4*)(hp + k);
                        a0 = fmaf(wv.x, hv.x, a0); a1 = fmaf(wv.y, hv.y, a1);
                        a2 = fmaf(wv.z, hv.z, a2); a3 = fmaf(wv.w, hv.w, a3);
                    }
                    sm.a.gM[q][jc][jj][bb] = (a0 + a1) + (a2 + a3);
                }
            }
            __syncthreads();
            if (q < 4) {
                hd0 = sm.a.gA[q][0][jj][bb] + sm.a.gA[q + 4][0][jj][bb] + bias0;
                hd1 = sm.a.gA[q][1][jj][bb] + sm.a.gA[q + 4][1][jj][bb] + bias1;
            }
            if (wg < 5 && q == 0 && t > 0) {
#pragma unroll
                for (int jc = 0; jc < 2; ++jc) {
                    int mr = wg * 16 + jc * 8 + jj;
                    float mel = sm.a.gM[0][jc][jj][bb] + sm.a.gM[1][jc][jj][bb] +
                                sm.a.gM[2][jc][jj][bb] + sm.a.gM[3][jc][jj][bb] + mel_b[mr];
                    agw_f(DIN + bb * 128 + mr, mel);
                    out[bb * MEL_ * T + mr * T + (t - 1)] = mel;
                }
            }
            if (wg < 5) arrive(flags, wg, ph1);

            // alpha wait: 13 producers {0..4, 32..39}
            if (tid < 13) {
                int w = (tid < 5) ? tid : (27 + tid);
                while (agr_u(flags + w * 16) < ph1)
                    __builtin_amdgcn_s_sleep(4);
            }
            __syncthreads();
        } else {
            // -------- attention WG (no fence; DH via uncached scalars) --------
            sm.at.dh2[tid] = agr_f(DH + ab * 512 + tid);
            __syncthreads();

            // hW: row = tid (W_h = attn_W[:, :512], row stride 1536; L2-resident)
            {
                const float* wr = attn_W + (size_t)tid * 1536;
                float a0 = 0.f, a1 = 0.f, a2 = 0.f, a3 = 0.f;
#pragma unroll 8
                for (int k = 0; k < 512; k += 4) {
                    float4 wv = *(const float4*)(wr + k);
                    float4 hv = *(const float4*)&sm.at.dh2[k];
                    a0 = fmaf(wv.x, hv.x, a0); a1 = fmaf(wv.y, hv.y, a1);
                    a2 = fmaf(wv.z, hv.z, a2); a3 = fmaf(wv.w, hv.w, a3);
                }
                sm.at.hw[tid] = (a0 + a1) + (a2 + a3);
            }
            __syncthreads();

            // scores: s = tid&127, k-quarter kq = tid>>7
            {
                int s  = tid & 127;
                int kq = tid >> 7;
                const float* ep = ENCP + (ab * S_ + s) * 512 + kq * 128;
                const float* hp = sm.at.hw + kq * 128;
                const float* vv = attn_v + kq * 128;
                float a0 = 0.f, a1 = 0.f, a2 = 0.f, a3 = 0.f;
#pragma unroll 4
                for (int k = 0; k < 128; k += 4) {
                    float4 e4 = *(const float4*)(ep + k);
                    float4 h4 = *(const float4*)(hp + k);
                    float4 v4 = *(const float4*)(vv + k);
                    a0 = fmaf(tanh_f(e4.x + h4.x), v4.x, a0);
                    a1 = fmaf(tanh_f(e4.y + h4.y), v4.y, a1);
                    a2 = fmaf(tanh_f(e4.z + h4.z), v4.z, a2);
                    a3 = fmaf(tanh_f(e4.w + h4.w), v4.w, a3);
                }
                sm.at.tmp[kq][s] = (a0 + a1) + (a2 + a3);
            }
            __syncthreads();

            float sc = 0.f;
            if (tid < 128) {
                sc = sm.at.tmp[0][tid] + sm.at.tmp[1][tid] +
                     sm.at.tmp[2][tid] + sm.at.tmp[3][tid];
                sm.at.red[tid] = sc;
            }
            __syncthreads();
            for (int off = 64; off >= 1; off >>= 1) {
                if (tid < off) sm.at.red[tid] = fmaxf(sm.at.red[tid], sm.at.red[tid + off]);
                __syncthreads();
            }
            float mx = sm.at.red[0];
            __syncthreads();
            if (tid < 128) {
                float e = __expf(sc - mx);
                sm.at.att[tid] = e;
                sm.at.red[tid] = e;
            }
            __syncthreads();
            if (tid < 64) sm.at.red[tid] += sm.at.red[tid + 64];
            __syncthreads();
            for (int off = 32; off >= 1; off >>= 1) {
                if (tid < off) sm.at.red[tid] += sm.at.red[tid + off];
                __syncthreads();
            }
            float inv = 1.f / sm.at.red[0];

            // ctx: 2 dims/thread (ENC L2-resident)
            {
                int d = tid * 2;
                const float* ebase = ENC + (size_t)ab * S_ * 1024 + d;
                float acc0 = 0.f, acc1 = 0.f;
#pragma unroll 4
                for (int s2 = 0; s2 < 128; ++s2) {
                    float a = sm.at.att[s2];
                    float2 ev = *(const float2*)(ebase + (size_t)s2 * 1024);
                    acc0 = fmaf(a, ev.x, acc0);
                    acc1 = fmaf(a, ev.y, acc1);
                }
                agw_f(CTX + ab * 1024 + d,     acc0 * inv);
                agw_f(CTX + ab * 1024 + d + 1, acc1 * inv);
            }
            arrive(flags, wg, ph1);   // then straight to beta poll
        }

        // ================= phase B (gate WGs) =================
        if (wg < 32) {
            acq_fence(flags + wg * 16);          // make CTX/DIN visible
#pragma unroll
            for (int u = 0; u < 4; ++u) {
                int n = tid + u * 512;           // 0..2047 float4s
                int b2 = n >> 8, d4 = n & 255;
                *(float4*)&sm.b.ctx[b2][d4 * 4] = *(const float4*)(CTX + b2 * 1024 + d4 * 4);
            }
#pragma unroll
            for (int u = 0; u < 2; ++u) {
                int n = tid + u * 512;           // 0..1023 scalars
                int b2 = n >> 7, m = n & 127;
                sm.b.din[b2][m] = DIN[b2 * 128 + m];
            }
            __syncthreads();

#pragma unroll
            for (int jc = 0; jc < 2; ++jc) {
                int row = g * 512 + wg * 16 + jc * 8 + jj;
                const float* wih_row = dec_Wih + (size_t)row * 1104;
                int lo = kh2 * 552;
                float a0 = 0.f, a1 = 0.f, a2 = 0.f, a3 = 0.f;
#pragma unroll 4
                for (int k = lo; k < lo + 552; k += 4) {
                    float4 wv = *(const float4*)(wih_row + k);
                    float4 xv = (k < 80) ? *(const float4*)&sm.b.din[bb][k]
                                         : *(const float4*)&sm.b.ctx[bb][k - 80];
                    a0 = fmaf(wv.x, xv.x, a0); a1 = fmaf(wv.y, xv.y, a1);
                    a2 = fmaf(wv.z, xv.z, a2); a3 = fmaf(wv.w, xv.w, a3);
                }
                float hdv = (q < 4) ? (jc ? hd1 : hd0) : 0.f;
                sm.b.gB[q][jc][jj][bb] = (a0 + a1) + (a2 + a3) + hdv;
            }
            __syncthreads();
            if (q == 0) {
#pragma unroll
                for (int jc = 0; jc < 2; ++jc) {
                    float gi = sm.b.gB[0][jc][jj][bb] + sm.b.gB[4][jc][jj][bb];
                    float gf = sm.b.gB[1][jc][jj][bb] + sm.b.gB[5][jc][jj][bb];
                    float gg = sm.b.gB[2][jc][jj][bb] + sm.b.gB[6][jc][jj][bb];
                    float go = sm.b.gB[3][jc][jj][bb] + sm.b.gB[7][jc][jj][bb];
                    float cr = jc ? c_reg1 : c_reg0;
                    float c2 = sigm_f(gf) * cr + sigm_f(gi) * tanh_f(gg);
                    float h2 = sigm_f(go) * tanh_f(c2);
                    if (jc) c_reg1 = c2; else c_reg0 = c2;
                    agw_f(DH + bb * 512 + wg * 16 + jc * 8 + jj, h2);
                }
            }
            arrive(flags, wg, ph2);
        }

        // beta wait: all 40 real WGs poll the 32 gate WGs
        if (tid < 32) {
            while (agr_u(flags + tid * 16) < ph2)
                __builtin_amdgcn_s_sleep(4);
        }
        __syncthreads();
    }

    // ---- final mel (t = T-1): WGs 0..4 ----
    if (wg < 5) {
        acq_fence(flags + wg * 16);
#pragma unroll
        for (int u = 0; u < 2; ++u) {
            int n = tid + u * 512;
            int b2 = n >> 7, k4 = n & 127;
            *(float4*)&sm.a.dh[b2][k4 * 4] = *(const float4*)(DH + b2 * 512 + k4 * 4);
        }
        __syncthreads();
        if (q < 4) {
#pragma unroll
            for (int jc = 0; jc < 2; ++jc) {
                int mr = wg * 16 + jc * 8 + jj;
                const float* wp = mel_W + (size_t)mr * 512 + q * 128;
                const float* hp = &sm.a.dh[bb][q * 128];
                float a0 = 0.f, a1 = 0.f, a2 = 0.f, a3 = 0.f;
#pragma unroll 8
                for (int k = 0; k < 128; k += 4) {
                    float4 wv = *(const float4*)(wp + k);
                    float4 hv = *(const float4*)(hp + k);
                    a0 = fmaf(wv.x, hv.x, a0); a1 = fmaf(wv.y, hv.y, a1);
                    a2 = fmaf(wv.z, hv.z, a2); a3 = fmaf(wv.w, hv.w, a3);
                }
                sm.a.gM[q][jc][jj][bb] = (a0 + a1) + (a2 + a3);
            }
        }
        __syncthreads();
        if (q == 0) {
#pragma unroll
            for (int jc = 0; jc < 2; ++jc) {
                int mr = wg * 16 + jc * 8 + jj;
                float mel = sm.a.gM[0][jc][jj][bb] + sm.a.gM[1][jc][jj][bb] +
                            sm.a.gM[2][jc][jj][bb] + sm.a.gM[3][jc][jj][bb] + mel_b[mr];
                out[bb * MEL_ * T + mr * T + (T - 1)] = mel;
            }
        }
    }

    // release heaters (wg 0 finishes last among producers of final output)
    __syncthreads();
    if (wg == 0 && tid == 0)
        agw_u(done, 1u);
}

// ---------------- host launch ----------------
extern "C" void kernel_launch(void* const* d_in, const int* in_sizes, int n_in,
                              void* d_out, int out_size, void* d_ws, size_t ws_size,
                              hipStream_t stream) {
    const int*   text  = (const int*)d_in[0];
    const float* emb   = (const float*)d_in[2];
    const float* Wih00 = (const float*)d_in[3];
    const float* Whh00 = (const float*)d_in[4];
    const float* bih00 = (const float*)d_in[5];
    const float* bhh00 = (const float*)d_in[6];
    const float* Wih01 = (const float*)d_in[7];
    const float* Whh01 = (const float*)d_in[8];
    const float* bih01 = (const float*)d_in[9];
    const float* bhh01 = (const float*)d_in[10];
    const float* Wih10 = (const float*)d_in[11];
    const float* Whh10 = (const float*)d_in[12];
    const float* bih10 = (const float*)d_in[13];
    const float* bhh10 = (const float*)d_in[14];
    const float* Wih11 = (const float*)d_in[15];
    const float* Whh11 = (const float*)d_in[16];
    const float* bih11 = (const float*)d_in[17];
    const float* bhh11 = (const float*)d_in[18];
    const float* attn_W = (const float*)d_in[19];
    const float* attn_b = (const float*)d_in[20];
    const float* attn_v = (const float*)d_in[21];
    const float* dec_Wih = (const float*)d_in[22];
    const float* dec_Whh = (const float*)d_in[23];
    const float* dec_bih = (const float*)d_in[24];
    const float* dec_bhh = (const float*)d_in[25];
    const float* mel_W = (const float*)d_in[26];
    const float* mel_b = (const float*)d_in[27];

    float* ws = (float*)d_ws;
    unsigned* flags = (unsigned*)d_ws;
    float* out = (float*)d_out;
    int T = out_size / (B_ * MEL_);   // 200

    // zero flags (incl. done words) + recurrent state
    zero_kernel<<<ZERO_WORDS / 256, 256, 0, stream>>>(ws);

    // embedding
    embed_kernel<<<512, 256, 0, stream>>>(text, emb, ws + OFF_X0);

    // layer0 input projections (bias folded: bih + bhh)
    gemm_f32<<<dim3(32, 16), 256, 0, stream>>>(ws + OFF_X0, 512, Wih00, 512,
                                               bih00, bhh00, ws + OFF_GX0F, 2048, 512);
    gemm_f32<<<dim3(32, 16), 256, 0, stream>>>(ws + OFF_X0, 512, Wih01, 512,
                                               bih01, bhh01, ws + OFF_GX0B, 2048, 512);
    // layer0 recurrence (+128 heater WGs)
    lstm_kernel<<<256, 256, 0, stream>>>(ws + OFF_GX0F, ws + OFF_GX0B, Whh00, Whh01,
                                         ws + OFF_H0, ws + OFF_H0S, flags + FLG_L0,
                                         flags + DONE_L0);
    // layer1 input projections
    gemm_f32<<<dim3(32, 16), 256, 0, stream>>>(ws + OFF_H0, 1024, Wih10, 1024,
                                               bih10, bhh10, ws + OFF_GX1F, 2048, 1024);
    gemm_f32<<<dim3(32, 16), 256, 0, stream>>>(ws + OFF_H0, 1024, Wih11, 1024,
                                               bih11, bhh11, ws + OFF_GX1B, 2048, 1024);
    // layer1 recurrence -> enc (+heaters)
    lstm_kernel<<<256, 256, 0, stream>>>(ws + OFF_GX1F, ws + OFF_GX1B, Whh10, Whh11,
                                         ws + OFF_ENC, ws + OFF_H1S, flags + FLG_L1,
                                         flags + DONE_L1);
    // enc_part = enc @ W_e^T + attn_b   (W_e = attn_W[:, 512:], row stride 1536)
    gemm_f32<<<dim3(8, 16), 256, 0, stream>>>(ws + OFF_ENC, 1024, attn_W + 512, 1536,
                                              attn_b, nullptr, ws + OFF_ENCP, 512, 1024);
    // decoder: 32 gate WGs + 8 attention WGs + 216 heater WGs
    decoder_kernel<<<256, 512, 0, stream>>>(ws, attn_W, attn_v, dec_Wih, dec_Whh,
                                            dec_bih, dec_bhh, mel_W, mel_b, out, T,
                                            flags + FLG_DEC, flags + DONE_DEC);
}

// Round 8
// 14129.335 us; speedup vs baseline: 1.4793x; 1.4793x over previous
//
#include <hip/hip_runtime.h>

// ---------------- problem constants ----------------
#define B_ 8
#define S_ 128
#define H_ 512
#define G_ 2048   // 4H
#define MEL_ 80

// ---------------- ws layout (32-bit word offsets) ----------------
// decoder flags: per batch 1024 words: C-flags lines 0..15, A-flags 16..31, B line 32
#define FLG_DEC    0                    // 8 * 1024 = 8192
#define FLG_L0     8192                 // 16 groups * 128 words (8 flag lines)
#define FLG_L1     10240
#define OFF_H0S    12288                // lstm0 h [(dir*8+b)][2][512] = 16384
#define OFF_H1S    (OFF_H0S + 16384)    // 16384
#define OFF_DH     (OFF_H1S + 16384)    // dec h [b][512] = 4096
#define OFF_DIN    (OFF_DH + 4096)      // din [b][128] = 1024 (80 used)
#define OFF_HW     (OFF_DIN + 1024)     // [b][512] = 4096
#define OFF_CTX    (OFF_HW + 4096)      // [b][1024] = 8192
#define ZERO_WORDS (OFF_CTX + 8192)     // = 62464 = 244*256
#define OFF_X0     62464                        // [bs][512]   524288
#define OFF_GX0F   (OFF_X0 + 524288)            // [bs][2048] 2097152
#define OFF_GX0B   (OFF_GX0F + 2097152)
#define OFF_H0     (OFF_GX0B + 2097152)         // [bs][1024] 1048576
#define OFF_GX1F   (OFF_H0 + 1048576)
#define OFF_GX1B   (OFF_GX1F + 2097152)
#define OFF_ENC    (OFF_GX1B + 2097152)         // [bs][1024] 1048576
#define OFF_ENCP   (OFF_ENC + 1048576)          // [bs][512]   524288

// ---------------- helpers ----------------
__device__ __forceinline__ float sigm_f(float x) {
    x = fminf(fmaxf(x, -30.f), 30.f);
    return 1.f / (1.f + __expf(-x));
}
__device__ __forceinline__ float tanh_f(float x) {
    x = fminf(fmaxf(x, -15.f), 15.f);
    float e = __expf(2.f * x);
    return (e - 1.f) / (e + 1.f);
}

// device-scope (cross-XCD coherent) uncached scalar access for tiny state
__device__ __forceinline__ void agw_u(unsigned* p, unsigned v) {
    __hip_atomic_store(p, v, __ATOMIC_RELAXED, __HIP_MEMORY_SCOPE_AGENT);
}
__device__ __forceinline__ unsigned agr_u(const unsigned* p) {
    return __hip_atomic_load(p, __ATOMIC_RELAXED, __HIP_MEMORY_SCOPE_AGENT);
}
__device__ __forceinline__ void agw_f(float* p, float v) {
    agw_u((unsigned*)p, __float_as_uint(v));
}
__device__ __forceinline__ float agr_f(const float* p) {
    return __uint_as_float(agr_u((const unsigned*)p));
}

// poll nf flag lines (stride 16 words) until >= phase
__device__ __forceinline__ void poll_flags(const unsigned* flags, int nf, unsigned phase) {
    if ((int)threadIdx.x < nf) {
        while (agr_u(flags + threadIdx.x * 16) < phase)
            __builtin_amdgcn_s_sleep(1);
    }
    __syncthreads();
}

// drain own stores (they're device-scope -> at LLC once vmcnt==0), then arrive
__device__ __forceinline__ void set_flag(unsigned* flag, unsigned phase) {
    asm volatile("s_waitcnt vmcnt(0) lgkmcnt(0)" ::: "memory");
    __syncthreads();
    if (threadIdx.x == 0)
        agw_u(flag, phase);
}

// ---------------- zero init ----------------
__global__ __launch_bounds__(256) void zero_kernel(float* p) {
    p[blockIdx.x * 256 + threadIdx.x] = 0.f;
}

// ---------------- embedding ----------------
__global__ __launch_bounds__(256) void embed_kernel(const int* __restrict__ text,
                                                    const float* __restrict__ emb,
                                                    float* __restrict__ X) {
    int i = blockIdx.x * 256 + threadIdx.x;   // float4 id, 131072 total
    int bs = i >> 7;
    int h4 = i & 127;
    int ch = text[bs];
    ((float4*)X)[i] = ((const float4*)emb)[ch * 128 + h4];
}

// ---------------- f32 GEMM: C[M,N] = A[M,K] * W[N,K]^T + b1 (+ b2) ----------------
__global__ __launch_bounds__(256) void gemm_f32(const float* __restrict__ A, int lda,
                                                const float* __restrict__ W, int ldw,
                                                const float* __restrict__ b1,
                                                const float* __restrict__ b2,
                                                float* __restrict__ C, int ldc, int K) {
    __shared__ float As[32][68];
    __shared__ float Ws[32][68];
    int tid = threadIdx.x;
    int tx = tid & 15, ty = tid >> 4;
    int n0 = blockIdx.x * 64, m0 = blockIdx.y * 64;
    float acc[4][4] = {};
    int r  = tid >> 3;
    int c4 = (tid & 7) * 4;
    for (int k0 = 0; k0 < K; k0 += 32) {
        float4 a0 = *(const float4*)&A[(m0 + r) * lda + k0 + c4];
        float4 a1 = *(const float4*)&A[(m0 + r + 32) * lda + k0 + c4];
        float4 w0 = *(const float4*)&W[(n0 + r) * ldw + k0 + c4];
        float4 w1 = *(const float4*)&W[(n0 + r + 32) * ldw + k0 + c4];
        As[c4 + 0][r] = a0.x; As[c4 + 1][r] = a0.y; As[c4 + 2][r] = a0.z; As[c4 + 3][r] = a0.w;
        As[c4 + 0][r + 32] = a1.x; As[c4 + 1][r + 32] = a1.y; As[c4 + 2][r + 32] = a1.z; As[c4 + 3][r + 32] = a1.w;
        Ws[c4 + 0][r] = w0.x; Ws[c4 + 1][r] = w0.y; Ws[c4 + 2][r] = w0.z; Ws[c4 + 3][r] = w0.w;
        Ws[c4 + 0][r + 32] = w1.x; Ws[c4 + 1][r + 32] = w1.y; Ws[c4 + 2][r + 32] = w1.z; Ws[c4 + 3][r + 32] = w1.w;
        __syncthreads();
#pragma unroll 8
        for (int kk = 0; kk < 32; ++kk) {
            float4 av = *(const float4*)&As[kk][ty * 4];
            float4 wv = *(const float4*)&Ws[kk][tx * 4];
            acc[0][0] = fmaf(av.x, wv.x, acc[0][0]); acc[0][1] = fmaf(av.x, wv.y, acc[0][1]);
            acc[0][2] = fmaf(av.x, wv.z, acc[0][2]); acc[0][3] = fmaf(av.x, wv.w, acc[0][3]);
            acc[1][0] = fmaf(av.y, wv.x, acc[1][0]); acc[1][1] = fmaf(av.y, wv.y, acc[1][1]);
            acc[1][2] = fmaf(av.y, wv.z, acc[1][2]); acc[1][3] = fmaf(av.y, wv.w, acc[1][3]);
            acc[2][0] = fmaf(av.z, wv.x, acc[2][0]); acc[2][1] = fmaf(av.z, wv.y, acc[2][1]);
            acc[2][2] = fmaf(av.z, wv.z, acc[2][2]); acc[2][3] = fmaf(av.z, wv.w, acc[2][3]);
            acc[3][0] = fmaf(av.w, wv.x, acc[3][0]); acc[3][1] = fmaf(av.w, wv.y, acc[3][1]);
            acc[3][2] = fmaf(av.w, wv.z, acc[3][2]); acc[3][3] = fmaf(av.w, wv.w, acc[3][3]);
        }
        __syncthreads();
    }
#pragma unroll
    for (int i = 0; i < 4; ++i)
#pragma unroll
        for (int j = 0; j < 4; ++j) {
            int n = n0 + tx * 4 + j;
            int m = m0 + ty * 4 + i;
            float bias = b1[n] + (b2 ? b2[n] : 0.f);
            C[m * ldc + n] = acc[i][j] + bias;
        }
}

// ---------------- per-(dir,batch) LSTM: 128 WGs, 16 independent 8-WG groups ----
// wg = s + 8*g16 (s = slice 0..7, g16 = dir*8 + b): slice s -> XCD s (round-robin),
// so each XCD L2 caches only Whh slices s (f+b dirs = 1 MB), shared by 8 batches.
// One rendezvous per step (poll own group's 8 C-flags).
__global__ __launch_bounds__(256) void lstm_kernel(const float* __restrict__ GXf,
                                                   const float* __restrict__ GXb,
                                                   const float* __restrict__ Whh_f,
                                                   const float* __restrict__ Whh_b,
                                                   float* __restrict__ Hout,
                                                   float* __restrict__ hstate,
                                                   unsigned* __restrict__ flagsL) {
    int wg  = blockIdx.x;
    int s   = wg & 7;
    int g16 = wg >> 3;        // 0..15
    int dir = g16 >> 3;
    int b   = g16 & 7;
    const float* GX  = dir ? GXb : GXf;
    const float* Whh = dir ? Whh_b : Whh_f;
    float* hs = hstate + g16 * 1024;         // [2][512]
    unsigned* fg = flagsL + g16 * 128;       // 8 flag lines

    int tid = threadIdx.x;
    int c64 = tid & 63;
    int col = s * 64 + c64;
    int grow = (tid >> 6) * 512 + col;       // gate row (g = tid>>6)
    const float* wr = Whh + (size_t)grow * 512;

    __shared__ float hsh[512];
    __shared__ float gvL[4][64];

    float cst = 0.f;    // cell state, threads tid<64 (col = s*64+tid)

    for (int t = 0; t < 128; ++t) {
        poll_flags(fg, 8, (unsigned)t);
        // read full h_b (2 KB) uncached
        hsh[tid]       = agr_f(hs + (t & 1) * 512 + tid);
        hsh[tid + 256] = agr_f(hs + (t & 1) * 512 + 256 + tid);
        __syncthreads();

        int st = dir ? (127 - t) : t;
        float acc = GX[((size_t)b * S_ + st) * G_ + grow];
        float a0 = 0.f, a1 = 0.f, a2 = 0.f, a3 = 0.f;
#pragma unroll 8
        for (int k = 0; k < 512; k += 4) {
            float4 wv = *(const float4*)(wr + k);
            float4 hv = *(const float4*)&hsh[k];
            a0 = fmaf(wv.x, hv.x, a0); a1 = fmaf(wv.y, hv.y, a1);
            a2 = fmaf(wv.z, hv.z, a2); a3 = fmaf(wv.w, hv.w, a3);
        }
        gvL[tid >> 6][c64] = acc + (a0 + a1) + (a2 + a3);
        __syncthreads();

        float h2 = 0.f;
        if (tid < 64) {
            float gi = gvL[0][tid], gf = gvL[1][tid];
            float gg = gvL[2][tid], go = gvL[3][tid];
            float c2 = sigm_f(gf) * cst + sigm_f(gi) * tanh_f(gg);
            h2 = sigm_f(go) * tanh_f(c2);
            cst = c2;
            agw_f(hs + ((t & 1) ^ 1) * 512 + col, h2);
        }
        set_flag(fg + s * 16, (unsigned)(t + 1));
        // layer output: off critical path (after arrive)
        if (tid < 64)
            Hout[((size_t)b * S_ + st) * 1024 + dir * 512 + col] = h2;
    }
}

// ---------------- per-batch decoder: 136 WGs ----------------
// gate WG: wg = s + 16*b (s = slice 0..15, b = batch): slice s -> XCD s%8.
//   slice s owns h-cols [s*32,(s+1)*32): rows {g*512 + col}, 128 rows.
// attn WG: wg = 128 + b (XCD b): mel + hW-gather + scores + softmax + ctx.
// per-step: poll C(16) -> phaseA {hdec partial, hW slice} -> A_s;
//           attn: [mel from h] poll A(16) -> scores/softmax/ctx -> B;
//           gates: poll B -> phaseB {Wih gates + cell} -> write h -> C_s.
__global__ __launch_bounds__(256) void decoder_kernel(float* __restrict__ ws,
                                                      const float* __restrict__ attn_W,
                                                      const float* __restrict__ attn_v,
                                                      const float* __restrict__ dec_Wih,
                                                      const float* __restrict__ dec_Whh,
                                                      const float* __restrict__ dec_bih,
                                                      const float* __restrict__ dec_bhh,
                                                      const float* __restrict__ mel_W,
                                                      const float* __restrict__ mel_b,
                                                      float* __restrict__ out, int T,
                                                      unsigned* __restrict__ flags) {
    float* ENC  = ws + OFF_ENC;
    float* ENCP = ws + OFF_ENCP;
    float* DH   = ws + OFF_DH;
    float* DIN  = ws + OFF_DIN;
    float* HW   = ws + OFF_HW;
    float* CTX  = ws + OFF_CTX;

    int wg  = blockIdx.x;
    int tid = threadIdx.x;

    if (wg < 128) {
        // ================= gate WG (slice s, batch b) =================
        int s = wg & 15;
        int b = wg >> 4;
        unsigned* fC = flags + b * 1024;
        unsigned* fA = fC + 16 * 16;
        unsigned* fB = fC + 32 * 16;

        int r   = tid >> 1;                 // local row 0..127
        int half = tid & 1;
        int grow = (r >> 5) * 512 + s * 32 + (r & 31);
        const float* whh_half = dec_Whh + (size_t)grow * 512 + half * 256;
        const float* wih_half = dec_Wih + (size_t)grow * 1104 + half * 552;
        float bias_r = (half == 0) ? (dec_bih[grow] + dec_bhh[grow]) : 0.f;
        int r2 = tid >> 3, oct = tid & 7;   // hW mapping: 32 rows x 8 k-octs
        const float* wh_row = attn_W + (size_t)(s * 32 + r2) * 1536 + oct * 64;

        __shared__ float hsh[512];
        __shared__ float hdL[128][2];
        __shared__ float hwred[32][8];
        __shared__ float gBx[128][2];
        __shared__ float gv[128];
        __shared__ float xin[1104];

        float cst = 0.f;   // threads tid<32: col = s*32+tid

        for (int t = 0; t < T; ++t) {
            // ---- phase A ----
            poll_flags(fC, 16, (unsigned)t);
            hsh[tid]       = agr_f(DH + b * 512 + tid);
            hsh[tid + 256] = agr_f(DH + b * 512 + 256 + tid);
            __syncthreads();
            // hdec partial (own half of k)
            {
                const float* hp = hsh + half * 256;
                float a0 = 0.f, a1 = 0.f, a2 = 0.f, a3 = 0.f;
#pragma unroll 8
                for (int k = 0; k < 256; k += 4) {
                    float4 wv = *(const float4*)(whh_half + k);
                    float4 hv = *(const float4*)(hp + k);
                    a0 = fmaf(wv.x, hv.x, a0); a1 = fmaf(wv.y, hv.y, a1);
                    a2 = fmaf(wv.z, hv.z, a2); a3 = fmaf(wv.w, hv.w, a3);
                }
                hdL[r][half] = (a0 + a1) + (a2 + a3) + bias_r;
            }
            // hW slice: rows s*32..s*32+31
            {
                const float* hp = hsh + oct * 64;
                float w = 0.f;
#pragma unroll 8
                for (int k = 0; k < 64; k += 4) {
                    float4 wv = *(const float4*)(wh_row + k);
                    float4 hv = *(const float4*)(hp + k);
                    w = fmaf(wv.x, hv.x, w); w = fmaf(wv.y, hv.y, w);
                    w = fmaf(wv.z, hv.z, w); w = fmaf(wv.w, hv.w, w);
                }
                hwred[r2][oct] = w;
            }
            __syncthreads();
            if (tid < 32) {
                float hw = hwred[tid][0] + hwred[tid][1] + hwred[tid][2] + hwred[tid][3]
                         + hwred[tid][4] + hwred[tid][5] + hwred[tid][6] + hwred[tid][7];
                agw_f(HW + b * 512 + s * 32 + tid, hw);
            }
            set_flag(fA + s * 16, (unsigned)(t + 1));

            // ---- phase B ----
            poll_flags(fB, 1, (unsigned)(t + 1));
            for (int n = tid; n < 1104; n += 256)
                xin[n] = (n < 80) ? agr_f(DIN + b * 128 + n)
                                  : agr_f(CTX + b * 1024 + (n - 80));
            __syncthreads();
            {
                const float* xp = xin + half * 552;
                float a0 = 0.f, a1 = 0.f, a2 = 0.f, a3 = 0.f;
#pragma unroll 8
                for (int k = 0; k < 552; k += 4) {
                    float4 wv = *(const float4*)(wih_half + k);
                    float4 xv = *(const float4*)(xp + k);
                    a0 = fmaf(wv.x, xv.x, a0); a1 = fmaf(wv.y, xv.y, a1);
                    a2 = fmaf(wv.z, xv.z, a2); a3 = fmaf(wv.w, xv.w, a3);
                }
                gBx[r][half] = (a0 + a1) + (a2 + a3);
            }
            __syncthreads();
            if (tid < 128)
                gv[tid] = gBx[tid][0] + gBx[tid][1] + hdL[tid][0] + hdL[tid][1];
            __syncthreads();
            if (tid < 32) {
                float gi = gv[tid], gf = gv[32 + tid], gg = gv[64 + tid], go = gv[96 + tid];
                float c2 = sigm_f(gf) * cst + sigm_f(gi) * tanh_f(gg);
                float h2 = sigm_f(go) * tanh_f(c2);
                cst = c2;
                agw_f(DH + b * 512 + s * 32 + tid, h2);
            }
            set_flag(fC + s * 16, (unsigned)(t + 1));
        }
    } else {
        // ================= attention WG (batch b) =================
        int b = wg - 128;
        unsigned* fC = flags + b * 1024;
        unsigned* fA = fC + 16 * 16;
        unsigned* fB = fC + 32 * 16;

        __shared__ float hsh[512];
        __shared__ float hw2[512];
        __shared__ float scred[128][2];
        __shared__ float red[128];
        __shared__ float att[128];
        __shared__ float melp[80][2];

        int r = tid >> 1, half = tid & 1;

        for (int t = 0; t < T; ++t) {
            poll_flags(fC, 16, (unsigned)t);
            hsh[tid]       = agr_f(DH + b * 512 + tid);
            hsh[tid + 256] = agr_f(DH + b * 512 + 256 + tid);
            __syncthreads();

            // mel from h (= h2 of step t-1) -> din_t, out[t-1]
            if (t > 0) {
                if (tid < 160) {
                    const float* wp = mel_W + (size_t)r * 512 + half * 256;
                    const float* hp = hsh + half * 256;
                    float a0 = 0.f, a1 = 0.f, a2 = 0.f, a3 = 0.f;
#pragma unroll 8
                    for (int k = 0; k < 256; k += 4) {
                        float4 wv = *(const float4*)(wp + k);
                        float4 hv = *(const float4*)(hp + k);
                        a0 = fmaf(wv.x, hv.x, a0); a1 = fmaf(wv.y, hv.y, a1);
                        a2 = fmaf(wv.z, hv.z, a2); a3 = fmaf(wv.w, hv.w, a3);
                    }
                    melp[r][half] = (a0 + a1) + (a2 + a3);
                }
                __syncthreads();
                if (tid < 80) {
                    float mel = melp[tid][0] + melp[tid][1] + mel_b[tid];
                    agw_f(DIN + b * 128 + tid, mel);
                    out[b * MEL_ * T + tid * T + (t - 1)] = mel;   // drains later
                }
            }

            poll_flags(fA, 16, (unsigned)(t + 1));
            hw2[tid]       = agr_f(HW + b * 512 + tid);
            hw2[tid + 256] = agr_f(HW + b * 512 + 256 + tid);
            __syncthreads();

            // scores: s2 = r, k-half = half
            {
                const float* ep = ENCP + ((size_t)b * S_ + r) * 512 + half * 256;
                const float* hp = hw2 + half * 256;
                const float* vv = attn_v + half * 256;
                float a0 = 0.f, a1 = 0.f, a2 = 0.f, a3 = 0.f;
#pragma unroll 4
                for (int k = 0; k < 256; k += 4) {
                    float4 e4 = *(const float4*)(ep + k);
                    float4 h4 = *(const float4*)(hp + k);
                    float4 v4 = *(const float4*)(vv + k);
                    a0 = fmaf(tanh_f(e4.x + h4.x), v4.x, a0);
                    a1 = fmaf(tanh_f(e4.y + h4.y), v4.y, a1);
                    a2 = fmaf(tanh_f(e4.z + h4.z), v4.z, a2);
                    a3 = fmaf(tanh_f(e4.w + h4.w), v4.w, a3);
                }
                scred[r][half] = (a0 + a1) + (a2 + a3);
            }
            __syncthreads();
            float sc = 0.f;
            if (tid < 128) {
                sc = scred[tid][0] + scred[tid][1];
                red[tid] = sc;
            }
            __syncthreads();
            for (int off = 64; off >= 1; off >>= 1) {
                if (tid < off) red[tid] = fmaxf(red[tid], red[tid + off]);
                __syncthreads();
            }
            float mx = red[0];
            __syncthreads();
            if (tid < 128) {
                float e = __expf(sc - mx);
                att[tid] = e;
                red[tid] = e;
            }
            __syncthreads();
            if (tid < 64) red[tid] += red[tid + 64];
            __syncthreads();
            for (int off = 32; off >= 1; off >>= 1) {
                if (tid < off) red[tid] += red[tid + off];
                __syncthreads();
            }
            float inv = 1.f / red[0];

            // ctx: 4 cols/thread (coalesced float4 per ENC row)
            {
                int d = tid * 4;
                const float* ebase = ENC + (size_t)b * S_ * 1024 + d;
                float c0 = 0.f, c1 = 0.f, c2 = 0.f, c3 = 0.f;
#pragma unroll 4
                for (int s2 = 0; s2 < 128; ++s2) {
                    float a = att[s2];
                    float4 ev = *(const float4*)(ebase + (size_t)s2 * 1024);
                    c0 = fmaf(a, ev.x, c0); c1 = fmaf(a, ev.y, c1);
                    c2 = fmaf(a, ev.z, c2); c3 = fmaf(a, ev.w, c3);
                }
                agw_f(CTX + b * 1024 + d,     c0 * inv);
                agw_f(CTX + b * 1024 + d + 1, c1 * inv);
                agw_f(CTX + b * 1024 + d + 2, c2 * inv);
                agw_f(CTX + b * 1024 + d + 3, c3 * inv);
            }
            set_flag(fB, (unsigned)(t + 1));
        }

        // epilogue: final mel from final h -> out[T-1]
        poll_flags(fC, 16, (unsigned)T);
        hsh[tid]       = agr_f(DH + b * 512 + tid);
        hsh[tid + 256] = agr_f(DH + b * 512 + 256 + tid);
        __syncthreads();
        if (tid < 160) {
            const float* wp = mel_W + (size_t)r * 512 + half * 256;
            const float* hp = hsh + half * 256;
            float a0 = 0.f, a1 = 0.f, a2 = 0.f, a3 = 0.f;
#pragma unroll 8
            for (int k = 0; k < 256; k += 4) {
                float4 wv = *(const float4*)(wp + k);
                float4 hv = *(const float4*)(hp + k);
                a0 = fmaf(wv.x, hv.x, a0); a1 = fmaf(wv.y, hv.y, a1);
                a2 = fmaf(wv.z, hv.z, a2); a3 = fmaf(wv.w, hv.w, a3);
            }
            melp[r][half] = (a0 + a1) + (a2 + a3);
        }
        __syncthreads();
        if (tid < 80)
            out[b * MEL_ * T + tid * T + (T - 1)] = melp[tid][0] + melp[tid][1] + mel_b[tid];
    }
}

// ---------------- host launch ----------------
extern "C" void kernel_launch(void* const* d_in, const int* in_sizes, int n_in,
                              void* d_out, int out_size, void* d_ws, size_t ws_size,
                              hipStream_t stream) {
    const int*   text  = (const int*)d_in[0];
    const float* emb   = (const float*)d_in[2];
    const float* Wih00 = (const float*)d_in[3];
    const float* Whh00 = (const float*)d_in[4];
    const float* bih00 = (const float*)d_in[5];
    const float* bhh00 = (const float*)d_in[6];
    const float* Wih01 = (const float*)d_in[7];
    const float* Whh01 = (const float*)d_in[8];
    const float* bih01 = (const float*)d_in[9];
    const float* bhh01 = (const float*)d_in[10];
    const float* Wih10 = (const float*)d_in[11];
    const float* Whh10 = (const float*)d_in[12];
    const float* bih10 = (const float*)d_in[13];
    const float* bhh10 = (const float*)d_in[14];
    const float* Wih11 = (const float*)d_in[15];
    const float* Whh11 = (const float*)d_in[16];
    const float* bih11 = (const float*)d_in[17];
    const float* bhh11 = (const float*)d_in[18];
    const float* attn_W = (const float*)d_in[19];
    const float* attn_b = (const float*)d_in[20];
    const float* attn_v = (const float*)d_in[21];
    const float* dec_Wih = (const float*)d_in[22];
    const float* dec_Whh = (const float*)d_in[23];
    const float* dec_bih = (const float*)d_in[24];
    const float* dec_bhh = (const float*)d_in[25];
    const float* mel_W = (const float*)d_in[26];
    const float* mel_b = (const float*)d_in[27];

    float* ws = (float*)d_ws;
    unsigned* flags = (unsigned*)d_ws;
    float* out = (float*)d_out;
    int T = out_size / (B_ * MEL_);   // 200

    // zero flags + recurrent state
    zero_kernel<<<ZERO_WORDS / 256, 256, 0, stream>>>(ws);

    // embedding
    embed_kernel<<<512, 256, 0, stream>>>(text, emb, ws + OFF_X0);

    // layer0 input projections (bias folded: bih + bhh)
    gemm_f32<<<dim3(32, 16), 256, 0, stream>>>(ws + OFF_X0, 512, Wih00, 512,
                                               bih00, bhh00, ws + OFF_GX0F, 2048, 512);
    gemm_f32<<<dim3(32, 16), 256, 0, stream>>>(ws + OFF_X0, 512, Wih01, 512,
                                               bih01, bhh01, ws + OFF_GX0B, 2048, 512);
    // layer0 recurrence: 16 independent (dir,b) groups x 8 slice-WGs
    lstm_kernel<<<128, 256, 0, stream>>>(ws + OFF_GX0F, ws + OFF_GX0B, Whh00, Whh01,
                                         ws + OFF_H0, ws + OFF_H0S, flags + FLG_L0);
    // layer1 input projections
    gemm_f32<<<dim3(32, 16), 256, 0, stream>>>(ws + OFF_H0, 1024, Wih10, 1024,
                                               bih10, bhh10, ws + OFF_GX1F, 2048, 1024);
    gemm_f32<<<dim3(32, 16), 256, 0, stream>>>(ws + OFF_H0, 1024, Wih11, 1024,
                                               bih11, bhh11, ws + OFF_GX1B, 2048, 1024);
    // layer1 recurrence -> enc
    lstm_kernel<<<128, 256, 0, stream>>>(ws + OFF_GX1F, ws + OFF_GX1B, Whh10, Whh11,
                                         ws + OFF_ENC, ws + OFF_H1S, flags + FLG_L1);
    // enc_part = enc @ W_e^T + attn_b   (W_e = attn_W[:, 512:], row stride 1536)
    gemm_f32<<<dim3(8, 16), 256, 0, stream>>>(ws + OFF_ENC, 1024, attn_W + 512, 1536,
                                              attn_b, nullptr, ws + OFF_ENCP, 512, 1024);
    // decoder: 8 independent batch-groups (16 gate WGs + 1 attn WG each)
    decoder_kernel<<<136, 256, 0, stream>>>(ws, attn_W, attn_v, dec_Wih, dec_Whh,
                                            dec_bih, dec_bhh, mel_W, mel_b, out, T,
                                            flags + FLG_DEC);
}